// Round 21
// baseline (278.532 us; speedup 1.0000x reference)
//
#include <hip/hip_runtime.h>
#include <hip/hip_cooperative_groups.h>

#pragma clang fp contract(off)

namespace cg = cooperative_groups;

#define N_ANCH 321408
#define NQUAD (N_ANCH / 4)
#define KSEL 4096
#define POST 300
#define H1BINS 1024
#define H1BASE 0x3D40u   // remap: bin = (k>>16) - H1BASE + 1 ; bin 0 = invalid (k==0)
#define CANDCAP 16384
#define SUPCAP 16        // max stored suppression targets per row; overflow -> dense fallback
#define WW 256           // NMS window width (4 waves)
#define OVFCAP 32
#define NBLK 256         // cooperative grid size (1 block/CU guaranteed resident)
// zero region: scal(256) | sel2(32768) | rank(65536) | sup_cnt(16384)
#define ZERO_BYTES (256 + 32768 + 65536 + 16384)
#define ZERO_U4 (ZERO_BYTES / 16)

typedef unsigned int u32;
typedef unsigned long long u64;

__device__ __forceinline__ u32 key_of(float m) {
    float s = 1.0f / (1.0f + expf(-m));
    return (s >= 0.05f) ? __float_as_uint(s) : 0u;
}

__device__ __forceinline__ void decode_box(u64 cpack, const float* __restrict__ boxp,
                                           const float* __restrict__ anch, float b[7]) {
    u32 key = (u32)(cpack >> 32);
    u32 idx = ~((u32)(cpack & 0xFFFFFFFFull));
    if (key == 0u) idx = 0u;
    const float* a7 = anch + (size_t)idx * 7;
    const float* t7 = boxp + (size_t)idx * 7;
    float xa = a7[0], ya = a7[1], za = a7[2], wa = a7[3], la = a7[4], ha = a7[5], ra = a7[6];
    float xt = t7[0], yt = t7[1], zt = t7[2], wt = t7[3], lt_ = t7[4], ht = t7[5], rt = t7[6];
    za = za + ha * 0.5f;
    float diag = sqrtf(la * la + wa * wa);
    float xg = xt * diag + xa;
    float yg = yt * diag + ya;
    float zg = zt * ha + za;
    float lg = expf(lt_) * la;
    float wg = expf(wt) * wa;
    float hg = expf(ht) * ha;
    float rg = rt + ra;
    zg = zg - hg * 0.5f;
    b[0] = xg; b[1] = yg; b[2] = zg; b[3] = wg; b[4] = lg; b[5] = hg; b[6] = rg;
}

__device__ __forceinline__ float4 standup_box(const float b[7], float* areao) {
    float xg = b[0], yg = b[1], wg = b[3], lg = b[4], rg = b[6];
    float cc = cosf(rg), ss = sinf(rg);
    float dx = wg * 0.5f, dy = lg * 0.5f;
    const float sxs[4] = {-1.f, -1.f, 1.f, 1.f};
    const float sys[4] = {-1.f, 1.f, 1.f, -1.f};
    float minx = 1e30f, miny = 1e30f, maxx = -1e30f, maxy = -1e30f;
    #pragma unroll
    for (int k = 0; k < 4; ++k) {
        float cx = dx * sxs[k], cy = dy * sys[k];
        float px = cx * cc + cy * ss;
        float py = cx * (-ss) + cy * cc;
        px = px + xg; py = py + yg;
        minx = fminf(minx, px); maxx = fmaxf(maxx, px);
        miny = fminf(miny, py); maxy = fmaxf(maxy, py);
    }
    *areao = (maxx - minx) * (maxy - miny);
    return make_float4(minx, miny, maxx, maxy);
}

__global__ __launch_bounds__(256, 1) void k_mega(
        const float4* __restrict__ cls4, const float* __restrict__ boxp,
        const float* __restrict__ anch, const float* __restrict__ dirp,
        float* __restrict__ out, uint4* __restrict__ keys4,
        u32* __restrict__ hist_part, uint4* __restrict__ zbase,
        u32* __restrict__ scal, u64* __restrict__ sel2, u32* __restrict__ rank,
        u32* __restrict__ sup_cnt, u64* __restrict__ cand, u64* __restrict__ mask,
        u32* __restrict__ sup_ent, float4* __restrict__ bb, float* __restrict__ area) {
    cg::grid_group grid = cg::this_grid();
    int t = threadIdx.x;
    int bid = blockIdx.x;
    int lane = t & 63;
    int wave = t >> 6;

    __shared__ u32 h0[H1BINS], h1[H1BINS];
    __shared__ u32 shc[1024], sha[1024], shb[1024];
    __shared__ u64 ch[256];
    __shared__ float4 ob[256];
    __shared__ float oa[256];
    // serial-phase state
    __shared__ u64 ls_avail[64];
    __shared__ u32 ls_excl[64];
    __shared__ int ls_cand[WW];
    __shared__ u64 ls_m[WW][4];
    __shared__ u64 ls_wv[4];
    __shared__ u64 ls_unc[4];
    __shared__ u32 ls_ovf[OVFCAP];
    __shared__ u32 ls_novf;
    __shared__ u32 ls_keep[POST];

    // ---------------- P1: zero region + keys + per-block histogram partials --------
    for (int i = t; i < H1BINS; i += 256) { h0[i] = 0; h1[i] = 0; }
    __syncthreads();
    for (int g = bid * 256 + t; g < ZERO_U4; g += NBLK * 256)
        zbase[g] = make_uint4(0, 0, 0, 0);
    for (int g = bid * 256 + t; g < NQUAD; g += NBLK * 256) {
        float4 a = cls4[g * 3], b = cls4[g * 3 + 1], d = cls4[g * 3 + 2];
        u32 k0 = key_of(fmaxf(a.x, fmaxf(a.y, a.z)));
        u32 k1 = key_of(fmaxf(a.w, fmaxf(b.x, b.y)));
        u32 k2 = key_of(fmaxf(b.z, fmaxf(b.w, d.x)));
        u32 k3 = key_of(fmaxf(d.y, fmaxf(d.z, d.w)));
        keys4[g] = make_uint4(k0, k1, k2, k3);
        u32* hp = (t & 1) ? h1 : h0;
        atomicAdd(&hp[k0 ? ((k0 >> 16) - H1BASE + 1u) : 0u], 1u);
        atomicAdd(&hp[k1 ? ((k1 >> 16) - H1BASE + 1u) : 0u], 1u);
        atomicAdd(&hp[k2 ? ((k2 >> 16) - H1BASE + 1u) : 0u], 1u);
        atomicAdd(&hp[k3 ? ((k3 >> 16) - H1BASE + 1u) : 0u], 1u);
    }
    __syncthreads();
    for (int i = t; i < H1BINS; i += 256)
        hist_part[(size_t)i * NBLK + bid] = h0[i] + h1[i];   // [bin][block], contiguous
    grid.sync();
    // ---------------- P2: scan (block 0) ----------------
    if (bid == 0) {
        for (int u = t; u < 1024; u += 256) {
            int b = 1023 - u;                         // descending bins
            const u32* hp = hist_part + (size_t)b * NBLK;
            u32 s = 0;
            #pragma unroll 8
            for (int r = 0; r < NBLK; ++r) s += hp[r];
            shc[u] = s; sha[u] = s;
        }
        __syncthreads();
        u32* src = sha; u32* dst = shb;
        for (int off = 1; off < 1024; off <<= 1) {
            for (int u = t; u < 1024; u += 256)
                dst[u] = src[u] + ((u >= off) ? src[u - off] : 0u);
            __syncthreads();
            u32* tmp = src; src = dst; dst = tmp;
        }
        for (int u = t; u < 1024; u += 256) {
            u32 incl = src[u];
            u32 excl = incl - shc[u];
            int b = 1023 - u;
            if (excl < 4096u && incl >= 4096u)
                scal[8] = (b > 0) ? (u32)(b - 1) + H1BASE : 0u;
        }
        if (t == 0) scal[9] = src[1023] - shc[1023];  // total valid (minus bin 0)
    }
    grid.sync();
    // ---------------- P3: compact (wave-aggregated) ----------------
    {
        u32 thr16 = scal[8];
        int qmax = (NQUAD + NBLK * 256 - 1) / (NBLK * 256) * (NBLK * 256);
        for (int q = bid * 256 + t; q < qmax; q += NBLK * 256) {
            bool act = q < NQUAD;
            uint4 kv = act ? keys4[q] : make_uint4(0, 0, 0, 0);
            u32 i0 = (u32)q * 4u;
            bool p0 = kv.x && (kv.x >> 16) >= thr16;
            bool p1 = kv.y && (kv.y >> 16) >= thr16;
            bool p2 = kv.z && (kv.z >> 16) >= thr16;
            bool p3 = kv.w && (kv.w >> 16) >= thr16;
            u64 b0 = __ballot(p0), b1 = __ballot(p1), b2 = __ballot(p2), b3 = __ballot(p3);
            u32 n0 = (u32)__popcll(b0), n1 = (u32)__popcll(b1), n2 = (u32)__popcll(b2);
            u32 nw = n0 + n1 + n2 + (u32)__popcll(b3);
            u32 base = 0;
            if (lane == 0 && nw) base = atomicAdd(&scal[5], nw);
            base = (u32)__shfl((int)base, 0);
            u64 lt = (lane == 0) ? 0ull : (~0ull >> (64 - lane));
            if (p0) { u32 p = base + (u32)__popcll(b0 & lt);
                      if (p < CANDCAP) cand[p] = (((u64)kv.x) << 32) | (u32)(~(i0 + 0)); }
            if (p1) { u32 p = base + n0 + (u32)__popcll(b1 & lt);
                      if (p < CANDCAP) cand[p] = (((u64)kv.y) << 32) | (u32)(~(i0 + 1)); }
            if (p2) { u32 p = base + n0 + n1 + (u32)__popcll(b2 & lt);
                      if (p < CANDCAP) cand[p] = (((u64)kv.z) << 32) | (u32)(~(i0 + 2)); }
            if (p3) { u32 p = base + n0 + n1 + n2 + (u32)__popcll(b3 & lt);
                      if (p < CANDCAP) cand[p] = (((u64)kv.w) << 32) | (u32)(~(i0 + 3)); }
        }
    }
    grid.sync();
    // ---------------- P4: rank-by-counting tiles ----------------
    {
        u32 nc = scal[5]; if (nc > CANDCAP) nc = CANDCAP;
        u32 ntile = (nc + 255u) / 256u;
        for (u32 g = (u32)bid; g < ntile * ntile; g += NBLK) {
            u32 cb = (g / ntile) * 256u;
            u32 jb = (g % ntile) * 256u;
            __syncthreads();
            ch[t] = (jb + (u32)t < nc) ? cand[jb + t] : 0ull;
            __syncthreads();
            u32 me = cb + (u32)t;
            u64 mine = (me < nc) ? cand[me] : ~0ull;
            u32 r = 0;
            #pragma unroll 8
            for (int j = 0; j < 256; ++j) r += (ch[j] > mine) ? 1u : 0u;
            if (me < nc && r) atomicAdd(&rank[me], r);
        }
    }
    grid.sync();
    // ---------------- P5: scatter + decode + standup ----------------
    {
        u32 nc = scal[5]; if (nc > CANDCAP) nc = CANDCAP;
        u32 nvc = scal[9]; if (nvc > (u32)KSEL) nvc = (u32)KSEL;
        for (u32 g = (u32)(bid * 256 + t); g < (u32)CANDCAP; g += NBLK * 256) {
            if (g < nc) {
                u32 r = rank[g];
                if (r < (u32)KSEL) {
                    u64 cp = cand[g];
                    sel2[r] = cp;
                    float b[7];
                    decode_box(cp, boxp, anch, b);
                    float a;
                    bb[r] = standup_box(b, &a);
                    area[r] = a;
                }
            }
            if (g >= nvc && g < (u32)KSEL) {
                float b[7];
                decode_box(0ull, boxp, anch, b);
                float a;
                bb[g] = standup_box(b, &a);
                area[g] = a;
            }
        }
    }
    grid.sync();
    // ---------------- P6: IoU mask tiles + sparse lists (wave-synchronous) --------
    for (int g = bid; g < 16 * 64; g += NBLK) {
        int rb = g >> 4;
        int cb = (g & 15) * 4 + wave;
        int i = rb * 64 + lane;
        if (cb < rb) { mask[(size_t)i * 64 + cb] = 0ull; continue; }
        int jg0 = cb * 64;
        ob[wave * 64 + lane] = bb[jg0 + lane];
        oa[wave * 64 + lane] = area[jg0 + lane];
        float4 m4 = bb[i];
        float ma = area[i];
        u64 bits = 0;
        for (int j = 0; j < 64; ++j) {
            int jg = jg0 + j;
            if (jg == i) continue;
            float4 o = ob[wave * 64 + j];
            float ltx = fmaxf(m4.x, o.x), lty = fmaxf(m4.y, o.y);
            float rbx = fminf(m4.z, o.z), rby = fminf(m4.w, o.w);
            float wd = fmaxf(rbx - ltx, 0.0f), h = fmaxf(rby - lty, 0.0f);
            float inter = wd * h;
            float iou = inter / (ma + oa[wave * 64 + j] - inter + 1e-8f);
            if (iou > 0.5f) bits |= (1ULL << j);
        }
        mask[(size_t)i * 64 + cb] = bits;
        u64 bset = bits;
        while (bset) {
            int j = (int)__builtin_ctzll(bset);
            bset &= bset - 1;
            int jg = jg0 + j;
            if (jg > i) {
                u32 p = atomicAdd(&sup_cnt[i], 1u);
                if (p < SUPCAP) sup_ent[(size_t)i * SUPCAP + p] = (u32)jg;
            }
        }
    }
    grid.sync();
    if (bid != 0) return;
    // ---------------- P7: window-256 greedy NMS + fused final (block 0) -----------
    if (t < 64) {
        u32 nvt = scal[9];
        u32 nv = (nvt < (u32)KSEL) ? nvt : (u32)KSEL;
        int lo = t * 64;
        u64 a;
        if ((int)nv >= lo + 64) a = ~0ull;
        else if ((int)nv <= lo) a = 0ull;
        else a = (((u64)1) << (nv - lo)) - 1ull;
        ls_avail[t] = a;
    }
    __syncthreads();
    int cnt = 0;
    for (;;) {
        ls_m[t][0] = 0; ls_m[t][1] = 0; ls_m[t][2] = 0; ls_m[t][3] = 0;
        ls_cand[t] = -1;
        if (t == 0) ls_novf = 0;
        __syncthreads();
        if (t < 64) {
            u64 avail = ls_avail[t];
            u32 pc = (u32)__popcll(avail);
            u32 pre = pc;
            #pragma unroll
            for (int off = 1; off < 64; off <<= 1) {
                u32 y = __shfl_up(pre, (unsigned)off);
                if (lane >= off) pre += y;
            }
            u32 excl = pre - pc;
            ls_excl[t] = excl;
            if (pc && excl < (u32)WW) {
                u64 a = avail;
                u32 o = excl;
                while (a && o < (u32)WW) {
                    int b = (int)__builtin_ctzll(a);
                    a &= a - 1;
                    ls_cand[o++] = t * 64 + b;
                }
            }
        }
        __syncthreads();
        int cj = ls_cand[t];
        bool valid = cj >= 0;
        {
            u64 wvb = __ballot(valid);
            if (lane == 0) ls_wv[wave] = wvb;
        }
        if (ls_cand[0] < 0) break;
        int cs = valid ? cj : 0;
        const uint4* ep = (const uint4*)(sup_ent + (size_t)cs * SUPCAP);
        uint4 e0 = ep[0], e1 = ep[1], e2 = ep[2], e3 = ep[3];
        u32 scnt = sup_cnt[cs];
        if (!valid) scnt = 0;
        u32 ecap = (scnt < (u32)SUPCAP) ? scnt : (u32)SUPCAP;
        u32 ent[SUPCAP] = {e0.x, e0.y, e0.z, e0.w, e1.x, e1.y, e1.z, e1.w,
                           e2.x, e2.y, e2.z, e2.w, e3.x, e3.y, e3.z, e3.w};
        bool ovf = valid && (scnt > (u32)SUPCAP);
        #pragma unroll
        for (int e = 0; e < SUPCAP; ++e) {
            u32 r = ent[e];
            if ((u32)e < ecap && r < (u32)KSEL) {
                u64 aw = ls_avail[r >> 6];
                if ((aw >> (r & 63)) & 1ull) {
                    u64 below = (r & 63) ? (aw & ((1ull << (r & 63)) - 1ull)) : 0ull;
                    u32 slot = ls_excl[r >> 6] + (u32)__popcll(below);
                    if (slot < (u32)WW)
                        atomicOr(&ls_m[slot][t >> 6], 1ull << (t & 63));
                }
            }
        }
        if (ovf) { u32 p = atomicAdd(&ls_novf, 1u); if (p < OVFCAP) ls_ovf[p] = (u32)t; }
        __syncthreads();
        u32 novf = ls_novf; if (novf > OVFCAP) novf = OVFCAP;
        for (u32 oi = 0; oi < novf; ++oi) {
            int s = (int)ls_ovf[oi];
            int ci = ls_cand[s];
            if (t < 64) {
                u64 w = mask[(size_t)ci * 64 + t] & ls_avail[t];
                while (w) {
                    int b = (int)__builtin_ctzll(w);
                    w &= w - 1;
                    u64 aw = ls_avail[t];
                    u64 below = b ? (aw & ((1ull << b) - 1ull)) : 0ull;
                    u32 slot = ls_excl[t] + (u32)__popcll(below);
                    if (slot < (u32)WW && slot != (u32)s)
                        atomicOr(&ls_m[slot][s >> 6], 1ull << (s & 63));
                }
            }
        }
        __syncthreads();
        u64 my0 = ls_m[t][0], my1 = ls_m[t][1], my2 = ls_m[t][2], my3 = ls_m[t][3];
        bool unc = valid && ((my0 | my1 | my2 | my3) != 0ull);
        {
            u64 ub = __ballot(unc);
            if (lane == 0) ls_unc[wave] = ub;
        }
        __syncthreads();
        u64 wv0 = ls_wv[0], wv1 = ls_wv[1], wv2 = ls_wv[2], wv3 = ls_wv[3];
        u64 u0 = ls_unc[0], u1 = ls_unc[1], u2 = ls_unc[2], u3 = ls_unc[3];
        u64 c0 = wv0 & ~u0, c1 = wv1 & ~u1, c2 = wv2 & ~u2, c3 = wv3 & ~u3;
        #pragma unroll
        for (int blk = 0; blk < 4; ++blk) {
            u64 uw = (blk == 0) ? u0 : (blk == 1) ? u1 : (blk == 2) ? u2 : u3;
            while (uw) {
                int j2 = (int)__builtin_ctzll(uw);
                uw &= uw - 1;
                int j = blk * 64 + j2;
                u64 m0 = ls_m[j][0], m1 = ls_m[j][1], m2 = ls_m[j][2], m3 = ls_m[j][3];
                u64 sup = (m0 & c0) | (m1 & c1) | (m2 & c2) | (m3 & c3);
                if (!sup) {
                    if (blk == 0) c0 |= 1ull << j2;
                    else if (blk == 1) c1 |= 1ull << j2;
                    else if (blk == 2) c2 |= 1ull << j2;
                    else c3 |= 1ull << j2;
                }
            }
        }
        u64 myc = (t < 64) ? c0 : (t < 128) ? c1 : (t < 192) ? c2 : c3;
        bool amC = valid && ((myc >> (t & 63)) & 1ull);
        {
            u32 rk = 0;
            if (wave > 0) rk += (u32)__popcll(c0);
            if (wave > 1) rk += (u32)__popcll(c1);
            if (wave > 2) rk += (u32)__popcll(c2);
            u64 below = (t & 63) ? (myc & ((1ull << (t & 63)) - 1ull)) : 0ull;
            rk += (u32)__popcll(below);
            if (amC && cnt + (int)rk < POST) ls_keep[cnt + rk] = (u32)cj;
        }
        int tot = (int)(__popcll(c0) + __popcll(c1) + __popcll(c2) + __popcll(c3));
        if (cnt + tot >= POST) { cnt = POST; break; }
        cnt += tot;
        if (amC) {
            #pragma unroll
            for (int e = 0; e < SUPCAP; ++e) {
                u32 r = ent[e];
                if ((u32)e < ecap && r < (u32)KSEL)
                    atomicAnd(&ls_avail[r >> 6], ~(1ull << (r & 63)));
            }
            atomicAnd(&ls_avail[cj >> 6], ~(1ull << (cj & 63)));
        }
        for (u32 oi = 0; oi < novf; ++oi) {
            int s = (int)ls_ovf[oi];
            u64 sc = (s < 64) ? c0 : (s < 128) ? c1 : (s < 192) ? c2 : c3;
            if ((sc >> (s & 63)) & 1ull) {
                int ci = ls_cand[s];
                if (t < 64) {
                    u64 w = mask[(size_t)ci * 64 + t];
                    if (w) atomicAnd(&ls_avail[t], ~w);
                }
            }
        }
        __syncthreads();
    }
    __syncthreads();
    u32 m = (u32)(cnt < POST ? cnt : POST);
    const float* clsf = (const float*)cls4;
    float* obp = out;
    float* os = out + POST * 7;
    float* ol = os + POST;
    float* ov = ol + POST;
    for (int o = t; o < POST; o += 256) {
        if (o < (int)m) {
            u32 r = ls_keep[o];
            u64 cp = sel2[r];
            u32 key = (u32)(cp >> 32);
            u32 i = ~((u32)(cp & 0xFFFFFFFFull));
            float b[7];
            decode_box(cp, boxp, anch, b);
            float d0 = dirp[(size_t)i * 2], d1 = dirp[(size_t)i * 2 + 1];
            int dl = (d1 > d0) ? 1 : 0;
            int pos = (b[6] > 0.0f) ? 1 : 0;
            if (pos ^ dl) b[6] = b[6] + 3.14159265358979323846f;
            for (int q = 0; q < 7; ++q) obp[(size_t)o * 7 + q] = b[q];
            os[o] = __uint_as_float(key);
            float t0 = 1.0f / (1.0f + expf(-clsf[(size_t)i * 3]));
            float t1 = 1.0f / (1.0f + expf(-clsf[(size_t)i * 3 + 1]));
            float t2 = 1.0f / (1.0f + expf(-clsf[(size_t)i * 3 + 2]));
            int lab = 0; float best = t0;
            if (t1 > best) { lab = 1; best = t1; }
            if (t2 > best) { lab = 2; }
            ol[o] = (float)lab;
            ov[o] = 1.0f;
        } else {
            for (int q = 0; q < 7; ++q) obp[(size_t)o * 7 + q] = 0.0f;
            os[o] = 0.0f;
            ol[o] = -1.0f;
            ov[o] = 0.0f;
        }
    }
}

extern "C" void kernel_launch(void* const* d_in, const int* in_sizes, int n_in,
                              void* d_out, int out_size, void* d_ws, size_t ws_size,
                              hipStream_t stream) {
    const float* box_preds = (const float*)d_in[0];
    const float* cls_preds = (const float*)d_in[1];
    const float* dir_preds = (const float*)d_in[2];
    const float* anchors   = (const float*)d_in[3];
    float* out = (float*)d_out;

    unsigned char* w = (unsigned char*)d_ws;
    size_t off = 0;
    auto nxt = [&](size_t bytes) -> void* {
        void* p = (void*)(w + off);
        off = (off + bytes + 255) & ~(size_t)255;
        return p;
    };
    // zero region (contiguous, zeroed in P1): scal | sel2 | rank | sup_cnt
    u32* scal      = (u32*)nxt(64 * 4);                //   256 B
    u64* sel2      = (u64*)nxt((size_t)KSEL * 8);      // 32768 B
    u32* rank      = (u32*)nxt((size_t)CANDCAP * 4);   // 65536 B
    u32* sup_cnt   = (u32*)nxt((size_t)KSEL * 4);      // 16384 B
    u32* hist_part = (u32*)nxt((size_t)NBLK * H1BINS * 4);
    u64* cand      = (u64*)nxt((size_t)CANDCAP * 8);
    u64* mask      = (u64*)nxt((size_t)KSEL * 64 * 8);
    u32* sup_ent   = (u32*)nxt((size_t)KSEL * SUPCAP * 4);
    float4* bb     = (float4*)nxt((size_t)KSEL * 16);
    float* area    = (float*)nxt((size_t)KSEL * 4);
    u32* keys      = (u32*)nxt((size_t)N_ANCH * 4);

    const float4* cls4 = (const float4*)cls_preds;
    uint4* keys4 = (uint4*)keys;
    uint4* zbase = (uint4*)scal;
    void* args[] = {(void*)&cls4, (void*)&box_preds, (void*)&anchors, (void*)&dir_preds,
                    (void*)&out, (void*)&keys4, (void*)&hist_part, (void*)&zbase,
                    (void*)&scal, (void*)&sel2, (void*)&rank, (void*)&sup_cnt,
                    (void*)&cand, (void*)&mask, (void*)&sup_ent, (void*)&bb,
                    (void*)&area};
    (void)hipLaunchCooperativeKernel((void*)k_mega, dim3(NBLK), dim3(256), args, 0, stream);
}

// Round 22
// 84.658 us; speedup vs baseline: 3.2901x; 3.2901x over previous
//
#include <hip/hip_runtime.h>

#pragma clang fp contract(off)

#define N_ANCH 321408
#define NQUAD (N_ANCH / 4)
#define NKB 79           // ceil(NQUAD/1024) k_keys blocks
#define KSEL 4096
#define POST 300
#define H1BINS 1024
#define H1BASE 0x3D40u   // remap: bin = (k>>16) - H1BASE + 1 ; bin 0 = invalid (k==0)
#define CANDCAP 16384
#define SUPCAP 16        // max stored suppression targets per row; overflow -> dense fallback
#define WW 256           // NMS window width (4 waves)
#define OVFCAP 32
// zero region: scal(256) | sel2(32768) | rank(65536) | sup_cnt(16384)
#define ZERO_BYTES (256 + 32768 + 65536 + 16384)
#define ZERO_U4 (ZERO_BYTES / 16)

typedef unsigned int u32;
typedef unsigned long long u64;

__device__ __forceinline__ u32 key_of(float m) {
    float s = 1.0f / (1.0f + expf(-m));
    return (s >= 0.05f) ? __float_as_uint(s) : 0u;
}

// ---------------- scoring + per-block histogram partials + workspace zeroing ----------
__global__ __launch_bounds__(1024) void k_keys(const float4* __restrict__ cls4,
                                               uint4* __restrict__ keys4,
                                               u32* __restrict__ hist_part,
                                               uint4* __restrict__ zbase) {
    __shared__ u32 h0[H1BINS], h1[H1BINS];
    int t = threadIdx.x;
    h0[t] = 0; h1[t] = 0;
    __syncthreads();
    int g = blockIdx.x * 1024 + t;
    if (g < ZERO_U4) zbase[g] = make_uint4(0, 0, 0, 0);
    if (g < NQUAD) {
        float4 a = cls4[g * 3], b = cls4[g * 3 + 1], d = cls4[g * 3 + 2];
        u32 k0 = key_of(fmaxf(a.x, fmaxf(a.y, a.z)));
        u32 k1 = key_of(fmaxf(a.w, fmaxf(b.x, b.y)));
        u32 k2 = key_of(fmaxf(b.z, fmaxf(b.w, d.x)));
        u32 k3 = key_of(fmaxf(d.y, fmaxf(d.z, d.w)));
        keys4[g] = make_uint4(k0, k1, k2, k3);
        u32* hp = (t & 1) ? h1 : h0;
        atomicAdd(&hp[k0 ? ((k0 >> 16) - H1BASE + 1u) : 0u], 1u);
        atomicAdd(&hp[k1 ? ((k1 >> 16) - H1BASE + 1u) : 0u], 1u);
        atomicAdd(&hp[k2 ? ((k2 >> 16) - H1BASE + 1u) : 0u], 1u);
        atomicAdd(&hp[k3 ? ((k3 >> 16) - H1BASE + 1u) : 0u], 1u);
    }
    __syncthreads();
    hist_part[blockIdx.x * H1BINS + t] = h0[t] + h1[t];   // plain store, no atomics
}

// sum 79 partials per bin, scan from the top: crossing bin + total valid count
__global__ __launch_bounds__(1024) void k_scan1(const u32* __restrict__ hist_part,
                                                u32* scal) {
    __shared__ u32 sh[1024];
    int t = threadIdx.x;
    int b = 1023 - t;                 // descending bins
    u32 s = 0;
    for (int r = 0; r < NKB; ++r) s += hist_part[r * H1BINS + b];
    sh[t] = s;
    __syncthreads();
    for (int off = 1; off < 1024; off <<= 1) {
        u32 x = sh[t];
        u32 y = (t >= off) ? sh[t - off] : 0u;
        __syncthreads();
        sh[t] = x + y;
        __syncthreads();
    }
    u32 incl = sh[t];
    u32 excl = incl - s;
    if (excl < 4096u && incl >= 4096u) {
        scal[8] = (b > 0) ? (u32)(b - 1) + H1BASE : 0u;   // actual upper-16 of crossing bin
    }
    if (t == 1023) scal[9] = incl - s;                    // total valid (minus bin 0)
}

// all candidates in bins >= crossing bin; wave-aggregated atomic, vectorized reads
__global__ __launch_bounds__(256) void k_compact(const uint4* __restrict__ keys4,
                                                 u32* scal, u64* __restrict__ cand) {
    int q = blockIdx.x * 256 + threadIdx.x;
    bool act = q < NQUAD;
    uint4 kv = act ? keys4[q] : make_uint4(0, 0, 0, 0);
    u32 thr16 = scal[8];
    int lane = threadIdx.x & 63;
    u32 i0 = (u32)q * 4u;
    bool p0 = kv.x && (kv.x >> 16) >= thr16;
    bool p1 = kv.y && (kv.y >> 16) >= thr16;
    bool p2 = kv.z && (kv.z >> 16) >= thr16;
    bool p3 = kv.w && (kv.w >> 16) >= thr16;
    u64 b0 = __ballot(p0), b1 = __ballot(p1), b2 = __ballot(p2), b3 = __ballot(p3);
    u32 n0 = (u32)__popcll(b0), n1 = (u32)__popcll(b1), n2 = (u32)__popcll(b2);
    u32 nw = n0 + n1 + n2 + (u32)__popcll(b3);
    u32 base = 0;
    if (lane == 0 && nw) base = atomicAdd(&scal[5], nw);
    base = (u32)__shfl((int)base, 0);
    u64 lt = (lane == 0) ? 0ull : (~0ull >> (64 - lane));
    if (p0) { u32 p = base + (u32)__popcll(b0 & lt);
              if (p < CANDCAP) cand[p] = (((u64)kv.x) << 32) | (u32)(~(i0 + 0)); }
    if (p1) { u32 p = base + n0 + (u32)__popcll(b1 & lt);
              if (p < CANDCAP) cand[p] = (((u64)kv.y) << 32) | (u32)(~(i0 + 1)); }
    if (p2) { u32 p = base + n0 + n1 + (u32)__popcll(b2 & lt);
              if (p < CANDCAP) cand[p] = (((u64)kv.z) << 32) | (u32)(~(i0 + 2)); }
    if (p3) { u32 p = base + n0 + n1 + n2 + (u32)__popcll(b3 & lt);
              if (p < CANDCAP) cand[p] = (((u64)kv.w) << 32) | (u32)(~(i0 + 3)); }
}

// 2D partial rank-by-counting (256-chunk; no fences)
__global__ __launch_bounds__(256) void k_rankpart(const u32* __restrict__ scal,
                                                  const u64* __restrict__ cand,
                                                  u32* __restrict__ rank) {
    __shared__ u64 ch[256];
    u32 nc = scal[5]; if (nc > CANDCAP) nc = CANDCAP;
    u32 cb = blockIdx.x * 256u;
    u32 jb = blockIdx.y * 256u;
    if (cb >= nc || jb >= nc) return;
    u32 t = threadIdx.x;
    ch[t] = (jb + t < nc) ? cand[jb + t] : 0ull;
    __syncthreads();
    u32 me = cb + t;
    u64 mine = (me < nc) ? cand[me] : ~0ull;
    u32 r = 0;
    #pragma unroll 8
    for (int j = 0; j < 256; ++j) r += (ch[j] > mine) ? 1u : 0u;
    if (me < nc && r) atomicAdd(&rank[me], r);
}

// ---------------- decode helpers ----------
__device__ __forceinline__ void decode_box(u64 cpack, const float* __restrict__ boxp,
                                           const float* __restrict__ anch, float b[7]) {
    u32 key = (u32)(cpack >> 32);
    u32 idx = ~((u32)(cpack & 0xFFFFFFFFull));
    if (key == 0u) idx = 0u;
    const float* a7 = anch + (size_t)idx * 7;
    const float* t7 = boxp + (size_t)idx * 7;
    float xa = a7[0], ya = a7[1], za = a7[2], wa = a7[3], la = a7[4], ha = a7[5], ra = a7[6];
    float xt = t7[0], yt = t7[1], zt = t7[2], wt = t7[3], lt_ = t7[4], ht = t7[5], rt = t7[6];
    za = za + ha * 0.5f;
    float diag = sqrtf(la * la + wa * wa);
    float xg = xt * diag + xa;
    float yg = yt * diag + ya;
    float zg = zt * ha + za;
    float lg = expf(lt_) * la;
    float wg = expf(wt) * wa;
    float hg = expf(ht) * ha;
    float rg = rt + ra;
    zg = zg - hg * 0.5f;
    b[0] = xg; b[1] = yg; b[2] = zg; b[3] = wg; b[4] = lg; b[5] = hg; b[6] = rg;
}

__device__ __forceinline__ float4 standup_box(const float b[7], float* areao) {
    float xg = b[0], yg = b[1], wg = b[3], lg = b[4], rg = b[6];
    float cc = cosf(rg), ss = sinf(rg);
    float dx = wg * 0.5f, dy = lg * 0.5f;
    const float sxs[4] = {-1.f, -1.f, 1.f, 1.f};
    const float sys[4] = {-1.f, 1.f, 1.f, -1.f};
    float minx = 1e30f, miny = 1e30f, maxx = -1e30f, maxy = -1e30f;
    #pragma unroll
    for (int k = 0; k < 4; ++k) {
        float cx = dx * sxs[k], cy = dy * sys[k];
        float px = cx * cc + cy * ss;
        float py = cx * (-ss) + cy * cc;
        px = px + xg; py = py + yg;
        minx = fminf(minx, px); maxx = fmaxf(maxx, px);
        miny = fminf(miny, py); maxy = fmaxf(maxy, py);
    }
    *areao = (maxx - minx) * (maxy - miny);
    return make_float4(minx, miny, maxx, maxy);
}

// fused scatter + decode + standup
__global__ __launch_bounds__(256) void k_scatdec(const u32* __restrict__ scal,
                                                 const u64* __restrict__ cand,
                                                 const u32* __restrict__ rank,
                                                 const float* __restrict__ boxp,
                                                 const float* __restrict__ anch,
                                                 u64* __restrict__ sel2,
                                                 float4* __restrict__ bb,
                                                 float* __restrict__ area) {
    u32 nc = scal[5]; if (nc > CANDCAP) nc = CANDCAP;
    u32 t = blockIdx.x * 256u + threadIdx.x;
    if (t < nc) {
        u32 r = rank[t];
        if (r < (u32)KSEL) {
            u64 cp = cand[t];
            sel2[r] = cp;
            float b[7];
            decode_box(cp, boxp, anch, b);
            float a;
            bb[r] = standup_box(b, &a);
            area[r] = a;
        }
    }
    u32 nvc = scal[9]; if (nvc > (u32)KSEL) nvc = (u32)KSEL;
    if (t >= nvc && t < (u32)KSEL) {
        float b[7];
        decode_box(0ull, boxp, anch, b);
        float a;
        bb[t] = standup_box(b, &a);
        area[t] = a;
    }
}

// 64x64 IoU mask tile + sparse suppression lists (rank i -> ranks j>i, IoU>0.5).
__global__ __launch_bounds__(64) void k_mask(const float4* __restrict__ bb,
                                             const float* __restrict__ area,
                                             u64* __restrict__ mask,
                                             u32* __restrict__ sup_cnt,
                                             u32* __restrict__ sup_ent) {
    int t = threadIdx.x;
    int rb = blockIdx.y, cb = blockIdx.x;
    int i = rb * 64 + t;
    if (cb < rb) { mask[(size_t)i * 64 + cb] = 0ull; return; }
    __shared__ float4 ob[64];
    __shared__ float oa[64];
    int jg0 = cb * 64;
    ob[t] = bb[jg0 + t];
    oa[t] = area[jg0 + t];
    __syncthreads();
    float4 m4 = bb[i];
    float ma = area[i];
    u64 bits = 0;
    for (int j = 0; j < 64; ++j) {
        int jg = jg0 + j;
        if (jg == i) continue;
        float4 o = ob[j];
        float ltx = fmaxf(m4.x, o.x), lty = fmaxf(m4.y, o.y);
        float rbx = fminf(m4.z, o.z), rby = fminf(m4.w, o.w);
        float w = fmaxf(rbx - ltx, 0.0f), h = fmaxf(rby - lty, 0.0f);
        float inter = w * h;
        float iou = inter / (ma + oa[j] - inter + 1e-8f);
        if (iou > 0.5f) bits |= (1ULL << j);
    }
    mask[(size_t)i * 64 + cb] = bits;
    u64 bset = bits;
    while (bset) {
        int j = (int)__builtin_ctzll(bset);
        bset &= bset - 1;
        int jg = jg0 + j;
        if (jg > i) {
            u32 p = atomicAdd(&sup_cnt[i], 1u);
            if (p < SUPCAP) sup_ent[(size_t)i * SUPCAP + p] = (u32)jg;
        }
    }
}

// 4-wave window-256 greedy NMS over sparse suppression lists + fused final output.
__global__ __launch_bounds__(256, 1) void k_serial(const u64* __restrict__ mask,
                                                   const u32* __restrict__ sup_cnt,
                                                   const u32* __restrict__ sup_ent,
                                                   const u64* __restrict__ sel2,
                                                   const float* __restrict__ boxp,
                                                   const float* __restrict__ anch,
                                                   const float* __restrict__ cls,
                                                   const float* __restrict__ dirp,
                                                   float* __restrict__ out,
                                                   const u32* __restrict__ scal) {
    int t = threadIdx.x;
    int lane = t & 63;
    int wave = t >> 6;
    __shared__ u64 ls_avail[64];
    __shared__ u32 ls_excl[64];
    __shared__ int ls_cand[WW];
    __shared__ u64 ls_m[WW][4];
    __shared__ u64 ls_wv[4];
    __shared__ u64 ls_unc[4];
    __shared__ u32 ls_ovf[OVFCAP];
    __shared__ u32 ls_novf;
    __shared__ u32 ls_keep[POST];

    if (t < 64) {
        u32 nvt = scal[9];
        u32 nv = (nvt < (u32)KSEL) ? nvt : (u32)KSEL;
        int lo = t * 64;
        u64 a;
        if ((int)nv >= lo + 64) a = ~0ull;
        else if ((int)nv <= lo) a = 0ull;
        else a = (((u64)1) << (nv - lo)) - 1ull;
        ls_avail[t] = a;
    }
    __syncthreads();

    int cnt = 0;
    for (;;) {
        ls_m[t][0] = 0; ls_m[t][1] = 0; ls_m[t][2] = 0; ls_m[t][3] = 0;
        ls_cand[t] = -1;
        if (t == 0) ls_novf = 0;
        __syncthreads();
        if (t < 64) {
            u64 avail = ls_avail[t];
            u32 pc = (u32)__popcll(avail);
            u32 pre = pc;
            #pragma unroll
            for (int off = 1; off < 64; off <<= 1) {
                u32 y = __shfl_up(pre, (unsigned)off);
                if (lane >= off) pre += y;
            }
            u32 excl = pre - pc;
            ls_excl[t] = excl;
            if (pc && excl < (u32)WW) {
                u64 a = avail;
                u32 o = excl;
                while (a && o < (u32)WW) {
                    int b = (int)__builtin_ctzll(a);
                    a &= a - 1;
                    ls_cand[o++] = t * 64 + b;
                }
            }
        }
        __syncthreads();
        int cj = ls_cand[t];
        bool valid = cj >= 0;
        {
            u64 wvb = __ballot(valid);
            if (lane == 0) ls_wv[wave] = wvb;
        }
        if (ls_cand[0] < 0) break;
        int cs = valid ? cj : 0;
        const uint4* ep = (const uint4*)(sup_ent + (size_t)cs * SUPCAP);
        uint4 e0 = ep[0], e1 = ep[1], e2 = ep[2], e3 = ep[3];
        u32 scnt = sup_cnt[cs];
        if (!valid) scnt = 0;
        u32 ecap = (scnt < (u32)SUPCAP) ? scnt : (u32)SUPCAP;
        u32 ent[SUPCAP] = {e0.x, e0.y, e0.z, e0.w, e1.x, e1.y, e1.z, e1.w,
                           e2.x, e2.y, e2.z, e2.w, e3.x, e3.y, e3.z, e3.w};
        bool ovf = valid && (scnt > (u32)SUPCAP);
        #pragma unroll
        for (int e = 0; e < SUPCAP; ++e) {
            u32 r = ent[e];
            if ((u32)e < ecap && r < (u32)KSEL) {
                u64 aw = ls_avail[r >> 6];
                if ((aw >> (r & 63)) & 1ull) {
                    u64 below = (r & 63) ? (aw & ((1ull << (r & 63)) - 1ull)) : 0ull;
                    u32 slot = ls_excl[r >> 6] + (u32)__popcll(below);
                    if (slot < (u32)WW)
                        atomicOr(&ls_m[slot][t >> 6], 1ull << (t & 63));
                }
            }
        }
        if (ovf) { u32 p = atomicAdd(&ls_novf, 1u); if (p < OVFCAP) ls_ovf[p] = (u32)t; }
        __syncthreads();
        u32 novf = ls_novf; if (novf > OVFCAP) novf = OVFCAP;
        for (u32 oi = 0; oi < novf; ++oi) {
            int s = (int)ls_ovf[oi];
            int ci = ls_cand[s];
            if (t < 64) {
                u64 w = mask[(size_t)ci * 64 + t] & ls_avail[t];
                while (w) {
                    int b = (int)__builtin_ctzll(w);
                    w &= w - 1;
                    u64 aw = ls_avail[t];
                    u64 below = b ? (aw & ((1ull << b) - 1ull)) : 0ull;
                    u32 slot = ls_excl[t] + (u32)__popcll(below);
                    if (slot < (u32)WW && slot != (u32)s)
                        atomicOr(&ls_m[slot][s >> 6], 1ull << (s & 63));
                }
            }
        }
        __syncthreads();
        u64 my0 = ls_m[t][0], my1 = ls_m[t][1], my2 = ls_m[t][2], my3 = ls_m[t][3];
        bool unc = valid && ((my0 | my1 | my2 | my3) != 0ull);
        {
            u64 ub = __ballot(unc);
            if (lane == 0) ls_unc[wave] = ub;
        }
        __syncthreads();
        u64 wv0 = ls_wv[0], wv1 = ls_wv[1], wv2 = ls_wv[2], wv3 = ls_wv[3];
        u64 u0 = ls_unc[0], u1 = ls_unc[1], u2 = ls_unc[2], u3 = ls_unc[3];
        u64 c0 = wv0 & ~u0, c1 = wv1 & ~u1, c2 = wv2 & ~u2, c3 = wv3 & ~u3;
        #pragma unroll
        for (int blk = 0; blk < 4; ++blk) {
            u64 uw = (blk == 0) ? u0 : (blk == 1) ? u1 : (blk == 2) ? u2 : u3;
            while (uw) {
                int j2 = (int)__builtin_ctzll(uw);
                uw &= uw - 1;
                int j = blk * 64 + j2;
                u64 m0 = ls_m[j][0], m1 = ls_m[j][1], m2 = ls_m[j][2], m3 = ls_m[j][3];
                u64 sup = (m0 & c0) | (m1 & c1) | (m2 & c2) | (m3 & c3);
                if (!sup) {
                    if (blk == 0) c0 |= 1ull << j2;
                    else if (blk == 1) c1 |= 1ull << j2;
                    else if (blk == 2) c2 |= 1ull << j2;
                    else c3 |= 1ull << j2;
                }
            }
        }
        u64 myc = (t < 64) ? c0 : (t < 128) ? c1 : (t < 192) ? c2 : c3;
        bool amC = valid && ((myc >> (t & 63)) & 1ull);
        {
            u32 rk = 0;
            if (wave > 0) rk += (u32)__popcll(c0);
            if (wave > 1) rk += (u32)__popcll(c1);
            if (wave > 2) rk += (u32)__popcll(c2);
            u64 below = (t & 63) ? (myc & ((1ull << (t & 63)) - 1ull)) : 0ull;
            rk += (u32)__popcll(below);
            if (amC && cnt + (int)rk < POST) ls_keep[cnt + rk] = (u32)cj;
        }
        int tot = (int)(__popcll(c0) + __popcll(c1) + __popcll(c2) + __popcll(c3));
        if (cnt + tot >= POST) { cnt = POST; break; }
        cnt += tot;
        if (amC) {
            #pragma unroll
            for (int e = 0; e < SUPCAP; ++e) {
                u32 r = ent[e];
                if ((u32)e < ecap && r < (u32)KSEL)
                    atomicAnd(&ls_avail[r >> 6], ~(1ull << (r & 63)));
            }
            atomicAnd(&ls_avail[cj >> 6], ~(1ull << (cj & 63)));
        }
        for (u32 oi = 0; oi < novf; ++oi) {
            int s = (int)ls_ovf[oi];
            u64 sc = (s < 64) ? c0 : (s < 128) ? c1 : (s < 192) ? c2 : c3;
            if ((sc >> (s & 63)) & 1ull) {
                int ci = ls_cand[s];
                if (t < 64) {
                    u64 w = mask[(size_t)ci * 64 + t];
                    if (w) atomicAnd(&ls_avail[t], ~w);
                }
            }
        }
        __syncthreads();
    }
    // ---- fused final output ----
    __syncthreads();
    u32 m = (u32)(cnt < POST ? cnt : POST);
    float* ob = out;
    float* os = out + POST * 7;
    float* ol = os + POST;
    float* ov = ol + POST;
    for (int o = t; o < POST; o += 256) {
        if (o < (int)m) {
            u32 r = ls_keep[o];
            u64 cp = sel2[r];
            u32 key = (u32)(cp >> 32);
            u32 i = ~((u32)(cp & 0xFFFFFFFFull));
            float b[7];
            decode_box(cp, boxp, anch, b);
            float d0 = dirp[(size_t)i * 2], d1 = dirp[(size_t)i * 2 + 1];
            int dl = (d1 > d0) ? 1 : 0;
            int pos = (b[6] > 0.0f) ? 1 : 0;
            if (pos ^ dl) b[6] = b[6] + 3.14159265358979323846f;
            for (int q = 0; q < 7; ++q) ob[(size_t)o * 7 + q] = b[q];
            os[o] = __uint_as_float(key);
            float s0 = 1.0f / (1.0f + expf(-cls[(size_t)i * 3]));
            float s1 = 1.0f / (1.0f + expf(-cls[(size_t)i * 3 + 1]));
            float s2 = 1.0f / (1.0f + expf(-cls[(size_t)i * 3 + 2]));
            int lab = 0; float best = s0;
            if (s1 > best) { lab = 1; best = s1; }
            if (s2 > best) { lab = 2; }
            ol[o] = (float)lab;
            ov[o] = 1.0f;
        } else {
            for (int q = 0; q < 7; ++q) ob[(size_t)o * 7 + q] = 0.0f;
            os[o] = 0.0f;
            ol[o] = -1.0f;
            ov[o] = 0.0f;
        }
    }
}

extern "C" void kernel_launch(void* const* d_in, const int* in_sizes, int n_in,
                              void* d_out, int out_size, void* d_ws, size_t ws_size,
                              hipStream_t stream) {
    const float* box_preds = (const float*)d_in[0];
    const float* cls_preds = (const float*)d_in[1];
    const float* dir_preds = (const float*)d_in[2];
    const float* anchors   = (const float*)d_in[3];
    float* out = (float*)d_out;

    unsigned char* w = (unsigned char*)d_ws;
    size_t off = 0;
    auto nxt = [&](size_t bytes) -> void* {
        void* p = (void*)(w + off);
        off = (off + bytes + 255) & ~(size_t)255;
        return p;
    };
    // zero region (contiguous, zeroed inline by k_keys): scal | sel2 | rank | sup_cnt
    u32* scal      = (u32*)nxt(64 * 4);                //   256 B
    u64* sel2      = (u64*)nxt((size_t)KSEL * 8);      // 32768 B
    u32* rank      = (u32*)nxt((size_t)CANDCAP * 4);   // 65536 B
    u32* sup_cnt   = (u32*)nxt((size_t)KSEL * 4);      // 16384 B
    u32* hist_part = (u32*)nxt((size_t)NKB * H1BINS * 4);
    u64* cand      = (u64*)nxt((size_t)CANDCAP * 8);
    u64* mask      = (u64*)nxt((size_t)KSEL * 64 * 8);
    u32* sup_ent   = (u32*)nxt((size_t)KSEL * SUPCAP * 4);
    float4* bb     = (float4*)nxt((size_t)KSEL * 16);
    float* area    = (float*)nxt((size_t)KSEL * 4);
    u32* keys      = (u32*)nxt((size_t)N_ANCH * 4);

    k_keys<<<NKB, 1024, 0, stream>>>((const float4*)cls_preds, (uint4*)keys,
                                     hist_part, (uint4*)scal);
    k_scan1<<<1, 1024, 0, stream>>>(hist_part, scal);
    k_compact<<<(NQUAD + 255) / 256, 256, 0, stream>>>((const uint4*)keys, scal, cand);
    dim3 rg(CANDCAP / 256, CANDCAP / 256);
    k_rankpart<<<rg, 256, 0, stream>>>(scal, cand, rank);
    k_scatdec<<<CANDCAP / 256, 256, 0, stream>>>(scal, cand, rank, box_preds, anchors,
                                                 sel2, bb, area);
    dim3 mg(64, 64);
    k_mask<<<mg, 64, 0, stream>>>(bb, area, mask, sup_cnt, sup_ent);
    k_serial<<<1, 256, 0, stream>>>(mask, sup_cnt, sup_ent, sel2, box_preds, anchors,
                                    cls_preds, dir_preds, out, scal);
}